// Round 16
// baseline (204.662 us; speedup 1.0000x reference)
//
#include <hip/hip_runtime.h>
#include <hip/hip_bf16.h>
#include <stdint.h>

#define DEVI __device__ __forceinline__

typedef __attribute__((ext_vector_type(8))) short bf16x8;
typedef __attribute__((ext_vector_type(4))) float f32x4;

DEVI float bf2f(short u) {
  union { unsigned int i; float f; } v;
  v.i = ((unsigned int)(unsigned short)u) << 16;
  return v.f;
}
DEVI short f2bf(float f) {
  union { float f; unsigned int i; } v; v.f = f;
  unsigned int r = v.i + 0x7FFFu + ((v.i >> 16) & 1u);  // RNE
  return (short)(r >> 16);
}

// LDS tile: row stride 64 shorts (128B), 16B-chunk XOR swizzle by (row&7).
DEVI bf16x8 ldsfrag(const short* t, int row, int k0) {
  int slot = k0 >> 3;
  return *(const bf16x8*)(t + row * 64 + ((slot ^ (row & 7)) << 3));
}

// async global->LDS, 16B per lane; LDS dest = uniform base + lane*16 (m97).
DEVI void gload16(const void* g, void* l) {
  __builtin_amdgcn_global_load_lds((const __attribute__((address_space(1))) void*)g,
                                   (__attribute__((address_space(3))) void*)l, 16, 0, 0);
}

// ---------------- fp32 -> bf16 convert (vectorized) ----------------
__global__ void k_cvt(const float* __restrict__ in, short* __restrict__ out, int n4) {
  int i = blockIdx.x * blockDim.x + threadIdx.x;
  if (i >= n4) return;
  float4 v = ((const float4*)in)[i];
  short4 o;
  o.x = f2bf(v.x); o.y = f2bf(v.y); o.z = f2bf(v.z); o.w = f2bf(v.w);
  ((short4*)out)[i] = o;
}

// ---------------- transpose + convert: in (R x C) f32 -> out (C x R) bf16 ----------------
__global__ void k_transpose_bf16(const float* __restrict__ in, short* __restrict__ outp,
                                 int R, int C) {
  __shared__ float tile[32][33];
  const int c0 = blockIdx.x * 32, r0 = blockIdx.y * 32;
  const int tx = threadIdx.x, ty = threadIdx.y;
  for (int i = ty; i < 32; i += 8) tile[i][tx] = in[(size_t)(r0 + i) * C + c0 + tx];
  __syncthreads();
  for (int i = ty; i < 32; i += 8) outp[(size_t)(c0 + i) * R + r0 + tx] = f2bf(tile[tx][i]);
}

// ---------------- RoPE tables TRANSPOSED: cos/sin[i][s], i<32, s<2048 ----------------
__global__ void k_rope(float* __restrict__ cosTt, float* __restrict__ sinTt) {
  int idx = blockIdx.x * blockDim.x + threadIdx.x;  // 32*2048
  int i = idx >> 11, s = idx & 2047;
  float inv = exp2f(-0.41524101186092034f * (float)i);
  float f = (float)s * inv;
  cosTt[idx] = cosf(f);
  sinTt[idx] = sinf(f);
}

// ---------------- fused QKV GEMM + bias + RoPE + head-split/permute (R10-proven) -------
__global__ __launch_bounds__(256) void k_gemm_qkv(const short* __restrict__ A,
                                                  const short* __restrict__ BT,
                                                  const float* __restrict__ bias,
                                                  const float* __restrict__ cosTt,
                                                  const float* __restrict__ sinTt,
                                                  short* __restrict__ qo,
                                                  short* __restrict__ ko,
                                                  short* __restrict__ vp) {
  __shared__ __align__(16) short smem[17408];  // K-loop: As|Bs; epi: [128][136]
  short* As = smem;
  short* Bs = smem + 8192;
  const int tid = threadIdx.x;
  const int lane = tid & 63, wid = tid >> 6;
  const int ln = lane & 15, grp = lane >> 4;
  const int wm = wid >> 1, wn = wid & 1;
  const int bx = blockIdx.x;
  const int r0 = blockIdx.y * 128, c0 = bx * 128;
  const int K = 1024;

  const short* aSrc[4];
  const short* bSrc[4];
  int ldst[4];
#pragma unroll
  for (int j = 0; j < 4; ++j) {
    int chunk = wid * 256 + j * 64 + lane;
    int row = chunk >> 3, gs = (chunk & 7) ^ (row & 7);
    aSrc[j] = A + (size_t)(r0 + row) * K + gs * 8;
    bSrc[j] = BT + (size_t)(c0 + row) * K + gs * 8;
    ldst[j] = (wid * 256 + j * 64) * 8;
  }

  f32x4 acc[4][4];
#pragma unroll
  for (int i = 0; i < 4; ++i)
#pragma unroll
    for (int j = 0; j < 4; ++j) acc[i][j] = (f32x4){0.f, 0.f, 0.f, 0.f};

  for (int kt = 0; kt < 16; ++kt) {
    __syncthreads();
#pragma unroll
    for (int j = 0; j < 4; ++j) {
      gload16(aSrc[j], &As[ldst[j]]);
      gload16(bSrc[j], &Bs[ldst[j]]);
      aSrc[j] += 64;
      bSrc[j] += 64;
    }
    __syncthreads();
#pragma unroll
    for (int ks = 0; ks < 2; ++ks) {
      const int k0 = ks * 32 + grp * 8;
      bf16x8 af[4], bfr[4];
#pragma unroll
      for (int mi = 0; mi < 4; ++mi) af[mi] = ldsfrag(As, wm * 64 + mi * 16 + ln, k0);
#pragma unroll
      for (int ni = 0; ni < 4; ++ni) bfr[ni] = ldsfrag(Bs, wn * 64 + ni * 16 + ln, k0);
#pragma unroll
      for (int mi = 0; mi < 4; ++mi)
#pragma unroll
        for (int ni = 0; ni < 4; ++ni)
          acc[mi][ni] = __builtin_amdgcn_mfma_f32_16x16x32_bf16(af[mi], bfr[ni], acc[mi][ni], 0, 0, 0);
    }
  }

  // ---------------- fused epilogue ----------------
  __syncthreads();
  const int third = bx >> 3;          // 0=q, 1=k, 2=v
  const int h0 = (bx & 7) * 2;
  const int b = r0 >> 11, sb = r0 & 2047;

  if (third < 2) {
    const float QS = (third == 0) ? 0.18033688011112042f : 1.0f;  // q: 0.125*log2(e)
#pragma unroll
    for (int mi = 0; mi < 4; ++mi) {
      const int s0 = sb + wm * 64 + mi * 16 + grp * 4;
      const int rowb = (wm * 64 + mi * 16 + grp * 4) * 136 + wn * 64;
#pragma unroll
      for (int ni = 0; ni < 2; ++ni) {
        const int d1 = ni * 16 + ln;
        float4 cv = *(const float4*)(cosTt + d1 * 2048 + s0);
        float4 sv = *(const float4*)(sinTt + d1 * 2048 + s0);
        const float b1 = bias[c0 + wn * 64 + d1];
        const float b2 = bias[c0 + wn * 64 + d1 + 32];
#pragma unroll
        for (int r = 0; r < 4; ++r) {
          float x1 = acc[mi][ni][r] + b1;
          float x2 = acc[mi][ni + 2][r] + b2;
          float c = ((const float*)&cv)[r], s = ((const float*)&sv)[r];
          smem[rowb + r * 136 + d1]      = f2bf((x1 * c - x2 * s) * QS);
          smem[rowb + r * 136 + d1 + 32] = f2bf((x1 * s + x2 * c) * QS);
        }
      }
    }
    __syncthreads();
    const int rloc = tid >> 1, ph = tid & 1;
    const int bh = b * 16 + h0 + ph;
    short* dst = (third == 0 ? qo : ko) + ((size_t)bh * 2048 + sb + rloc) * 64;
    const short* src = smem + rloc * 136 + ph * 64;
#pragma unroll
    for (int j = 0; j < 8; ++j) *(int4*)(dst + j * 8) = *(const int4*)(src + j * 8);
  } else {
#pragma unroll
    for (int mi = 0; mi < 4; ++mi) {
      const int rowb = (wm * 64 + mi * 16 + grp * 4) * 136 + wn * 64;
#pragma unroll
      for (int ni = 0; ni < 4; ++ni) {
        const float bv = bias[c0 + wn * 64 + ni * 16 + ln];
#pragma unroll
        for (int r = 0; r < 4; ++r)
          smem[rowb + r * 136 + ni * 16 + ln] = f2bf(acc[mi][ni][r] + bv);
      }
    }
    __syncthreads();
#pragma unroll
    for (int i = 0; i < 8; ++i) {
      const int g = i * 256 + tid;
      const int ph = g >> 10, tt = (g >> 9) & 1, cc2 = g & 511;
      const int ks = cc2 >> 8, mi = (cc2 >> 6) & 3, grp_ = (cc2 >> 4) & 3, ln_ = cc2 & 15;
      const int d = mi * 16 + ln_;
      bf16x8 o;
#pragma unroll
      for (int e = 0; e < 8; ++e) {
        const int key = tt * 64 + 32 * ks + 16 * (e >> 2) + 4 * grp_ + (e & 3);
        o[e] = smem[key * 136 + ph * 64 + d];
      }
      const int bh = b * 16 + h0 + ph;
      const int tg = (sb >> 6) + tt;
      *(bf16x8*)(vp + ((size_t)bh * 32 + tg) * 4096 + cc2 * 8) = o;
    }
  }
}

// ---------------- plain bf16 MFMA GEMM (out-proj, R10-proven): f32 out ----------------
__global__ __launch_bounds__(256) void k_gemm_out(const short* __restrict__ A,
                                                  const short* __restrict__ BT,
                                                  const float* __restrict__ bias,
                                                  float* __restrict__ outp,
                                                  int M, int N, int K) {
  __shared__ __align__(16) short As[128 * 64];
  __shared__ __align__(16) short Bs[128 * 64];
  const int tid = threadIdx.x;
  const int lane = tid & 63, wid = tid >> 6;
  const int ln = lane & 15, grp = lane >> 4;
  const int wm = wid >> 1, wn = wid & 1;
  const int r0 = blockIdx.y * 128, c0 = blockIdx.x * 128;

  const short* aSrc[4];
  const short* bSrc[4];
  int ldst[4];
#pragma unroll
  for (int j = 0; j < 4; ++j) {
    int chunk = wid * 256 + j * 64 + lane;
    int row = chunk >> 3, gs = (chunk & 7) ^ (row & 7);
    aSrc[j] = A + (size_t)(r0 + row) * K + gs * 8;
    bSrc[j] = BT + (size_t)(c0 + row) * K + gs * 8;
    ldst[j] = (wid * 256 + j * 64) * 8;
  }

  f32x4 acc[4][4];
#pragma unroll
  for (int i = 0; i < 4; ++i)
#pragma unroll
    for (int j = 0; j < 4; ++j) acc[i][j] = (f32x4){0.f, 0.f, 0.f, 0.f};

  const int nkt = K >> 6;
  for (int kt = 0; kt < nkt; ++kt) {
    __syncthreads();
#pragma unroll
    for (int j = 0; j < 4; ++j) {
      gload16(aSrc[j], &As[ldst[j]]);
      gload16(bSrc[j], &Bs[ldst[j]]);
      aSrc[j] += 64;
      bSrc[j] += 64;
    }
    __syncthreads();
#pragma unroll
    for (int ks = 0; ks < 2; ++ks) {
      const int k0 = ks * 32 + grp * 8;
      bf16x8 af[4], bfr[4];
#pragma unroll
      for (int mi = 0; mi < 4; ++mi) af[mi] = ldsfrag(As, wm * 64 + mi * 16 + ln, k0);
#pragma unroll
      for (int ni = 0; ni < 4; ++ni) bfr[ni] = ldsfrag(Bs, wn * 64 + ni * 16 + ln, k0);
#pragma unroll
      for (int mi = 0; mi < 4; ++mi)
#pragma unroll
        for (int ni = 0; ni < 4; ++ni)
          acc[mi][ni] = __builtin_amdgcn_mfma_f32_16x16x32_bf16(af[mi], bfr[ni], acc[mi][ni], 0, 0, 0);
    }
  }
#pragma unroll
  for (int ni = 0; ni < 4; ++ni) {
    const int col = c0 + wn * 64 + ni * 16 + ln;
    const float bv = bias[col];
#pragma unroll
    for (int mi = 0; mi < 4; ++mi) {
#pragma unroll
      for (int r = 0; r < 4; ++r) {
        const int rowg = r0 + wm * 64 + mi * 16 + grp * 4 + r;
        outp[(size_t)rowg * N + col] = acc[mi][ni][r] + bv;
      }
    }
  }
}

// ---------------- flash attention v16: single-buffer KVBLK=128 (occupancy probe) -------
// grid (qt=16, bh=64), 256 thr = 4 waves; QBLK=128 (32 q/wave), KVBLK=128.
// Single 32KB buffer (K 16KB swizzled | Vp 16KB fragment-linear) -> up to 4
// blocks/CU (vs dbuf's 2). R14-proven 2-barrier skeleton + R15-proven
// KVBLK=128 compute body. T1 XCD swizzle (R13-proven, FETCH 139->25MB).
// No-max exp2 softmax (scores bounded), l via ones-MFMA, asm v_cvt_pk.
__global__ __launch_bounds__(256) void k_attn(const short* __restrict__ Q,
                                              const short* __restrict__ Kk,
                                              const short* __restrict__ Vp,
                                              short* __restrict__ out) {
  __shared__ __align__(16) short smem[16384];  // K[0:8192) | V[8192:16384); epi reuses
  const int tid = threadIdx.x;
  const int lane = tid & 63, wid = tid >> 6;
  const int ln = lane & 15, grp = lane >> 4;
  const int L = blockIdx.y * 16 + blockIdx.x;       // 0..1023
  const int W = (L & 7) * 128 + (L >> 3);           // XCD-chunked work id
  const int qt = W & 15, bh = W >> 4;
  const int b = bh >> 4, h = bh & 15;

  bf16x8 qf[2][2];
#pragma unroll
  for (int g = 0; g < 2; ++g)
#pragma unroll
    for (int ks = 0; ks < 2; ++ks)
      qf[g][ks] = *(const bf16x8*)(Q + ((size_t)bh * 2048 + qt * 128 + wid * 32 + g * 16 + ln) * 64
                                   + ks * 32 + grp * 8);

  // staging: 1024 K-chunks + 1024 V-chunks of 16B per tile; 4 each per thread
  const short* kSrc[4];
  const short* vSrc[4];
  int ldk[4], ldv[4];
  {
    const short* kt0 = Kk + (size_t)bh * 2048 * 64;
    const short* vt0 = Vp + (size_t)bh * 32 * 4096;
#pragma unroll
    for (int j = 0; j < 4; ++j) {
      int c = j * 256 + wid * 64 + lane;
      int row = c >> 3, gs = (c & 7) ^ (row & 7);
      kSrc[j] = kt0 + (size_t)row * 64 + gs * 8;
      ldk[j] = (j * 256 + wid * 64) * 8;
      vSrc[j] = vt0 + (size_t)c * 8;
      ldv[j] = 8192 + (j * 256 + wid * 64) * 8;
    }
  }

  f32x4 acc[2][4];
  f32x4 accl[2];
#pragma unroll
  for (int g = 0; g < 2; ++g) {
    accl[g] = (f32x4){0.f, 0.f, 0.f, 0.f};
#pragma unroll
    for (int i = 0; i < 4; ++i) acc[g][i] = (f32x4){0.f, 0.f, 0.f, 0.f};
  }
  bf16x8 ones;
#pragma unroll
  for (int e = 0; e < 8; ++e) ones[e] = (short)0x3F80;  // bf16 1.0

  union PU { bf16x8 v; unsigned int u[4]; };

  for (int t = 0; t < 16; ++t) {
    __syncthreads();  // prev-tile LDS reads done (WAR)
#pragma unroll
    for (int j = 0; j < 4; ++j) {
      gload16(kSrc[j], &smem[ldk[j]]);
      gload16(vSrc[j], &smem[ldv[j]]);
      kSrc[j] += 8192;
      vSrc[j] += 8192;
    }
    __syncthreads();  // staging complete (compiler drains vmcnt)
    const short* Kb = smem;
    const short* Vb = smem + 8192;

    // ---- S^T = K Q^T : sf[g][ni][r] = S'[key=ni*16+grp*4+r][q(g)], ni 0..7 ----
    f32x4 sf[2][8];
#pragma unroll
    for (int g = 0; g < 2; ++g)
#pragma unroll
      for (int ni = 0; ni < 8; ++ni) sf[g][ni] = (f32x4){0.f, 0.f, 0.f, 0.f};
#pragma unroll
    for (int ks = 0; ks < 2; ++ks) {
      bf16x8 kf[8];
#pragma unroll
      for (int ni = 0; ni < 8; ++ni) kf[ni] = ldsfrag(Kb, ni * 16 + ln, ks * 32 + grp * 8);
      __builtin_amdgcn_s_setprio(1);
#pragma unroll
      for (int g = 0; g < 2; ++g)
#pragma unroll
        for (int ni = 0; ni < 8; ++ni)
          sf[g][ni] = __builtin_amdgcn_mfma_f32_16x16x32_bf16(kf[ni], qf[g][ks], sf[g][ni], 0, 0, 0);
      __builtin_amdgcn_s_setprio(0);
    }

    // ---- p = exp2(s); pack to bf16 (asm v_cvt_pk, R7-proven) ----
    PU pbf[2][4];
#pragma unroll
    for (int g = 0; g < 2; ++g) {
#pragma unroll
      for (int ni = 0; ni < 8; ++ni) {
        f32x4 s = sf[g][ni];
#pragma unroll
        for (int r = 0; r < 4; ++r) s[r] = __builtin_amdgcn_exp2f(s[r]);
        sf[g][ni] = s;
      }
#pragma unroll
      for (int ks2 = 0; ks2 < 4; ++ks2)
#pragma unroll
        for (int j = 0; j < 4; ++j) {
          float lo = sf[g][2 * ks2 + (j >> 1)][(j & 1) * 2];
          float hi = sf[g][2 * ks2 + (j >> 1)][(j & 1) * 2 + 1];
          unsigned int rr;
          asm("v_cvt_pk_bf16_f32 %0, %1, %2" : "=v"(rr) : "v"(lo), "v"(hi));
          pbf[g][ks2].u[j] = rr;
        }
    }

    // ---- O^T += V^T P ; l += 1^T P  (ks2 over 4 key-slices of 32) ----
#pragma unroll
    for (int ks2 = 0; ks2 < 4; ++ks2) {
      bf16x8 vf[4];
#pragma unroll
      for (int mi = 0; mi < 4; ++mi)
        vf[mi] = *(const bf16x8*)(Vb + (ks2 * 256 + mi * 64 + lane) * 8);
      __builtin_amdgcn_s_setprio(1);
#pragma unroll
      for (int g = 0; g < 2; ++g) {
#pragma unroll
        for (int mi = 0; mi < 4; ++mi)
          acc[g][mi] = __builtin_amdgcn_mfma_f32_16x16x32_bf16(vf[mi], pbf[g][ks2].v, acc[g][mi], 0, 0, 0);
        accl[g] = __builtin_amdgcn_mfma_f32_16x16x32_bf16(ones, pbf[g][ks2].v, accl[g], 0, 0, 0);
      }
      __builtin_amdgcn_s_setprio(0);
    }
  }

  // ---- epilogue: O^T/l -> swizzled LDS [q][d] -> coalesced global ----
  __syncthreads();
#pragma unroll
  for (int g = 0; g < 2; ++g) {
    const float inv = 1.0f / accl[g][0];
    const int q = wid * 32 + g * 16 + ln;
#pragma unroll
    for (int mi = 0; mi < 4; ++mi) {
      short4 p;
      p.x = f2bf(acc[g][mi][0] * inv);
      p.y = f2bf(acc[g][mi][1] * inv);
      p.z = f2bf(acc[g][mi][2] * inv);
      p.w = f2bf(acc[g][mi][3] * inv);
      int slot = mi * 2 + (grp >> 1);
      *(short4*)(&smem[q * 64 + ((slot ^ (q & 7)) << 3) + (grp & 1) * 4]) = p;
    }
  }
  __syncthreads();
  {
    const int row = tid >> 1, half = tid & 1;
#pragma unroll
    for (int j = 0; j < 4; ++j) {
      int c = half * 4 + j;
      int4 v = *(const int4*)(&smem[row * 64 + ((c ^ (row & 7)) << 3)]);
      *(int4*)(out + ((size_t)b * 2048 + qt * 128 + row) * 1024 + h * 64 + c * 8) = v;
    }
  }
}

extern "C" void kernel_launch(void* const* d_in, const int* in_sizes, int n_in,
                              void* d_out, int out_size, void* d_ws, size_t ws_size,
                              hipStream_t stream) {
  const float* x    = (const float*)d_in[0];
  const float* Wqkv = (const float*)d_in[1];
  const float* bqkv = (const float*)d_in[2];
  const float* Wout = (const float*)d_in[3];
  const float* bout = (const float*)d_in[4];
  float* out = (float*)d_out;

  char* p = (char*)d_ws;
  short* xb    = (short*)p; p += (size_t)8192 * 1024 * 2;
  short* wqkvT = (short*)p; p += (size_t)3072 * 1024 * 2;
  short* woutT = (short*)p; p += (size_t)1024 * 1024 * 2;
  float* cosTt = (float*)p; p += (size_t)32 * 2048 * 4;
  float* sinTt = (float*)p; p += (size_t)32 * 2048 * 4;
  short* qb    = (short*)p; p += (size_t)64 * 2048 * 64 * 2;
  short* kb    = (short*)p; p += (size_t)64 * 2048 * 64 * 2;
  short* vpb   = (short*)p; p += (size_t)64 * 2048 * 64 * 2;
  short* ao    = (short*)p; p += (size_t)8192 * 1024 * 2;

  k_cvt<<<8192 * 1024 / 4 / 256, 256, 0, stream>>>(x, xb, 8192 * 1024 / 4);
  k_transpose_bf16<<<dim3(3072 / 32, 1024 / 32), dim3(32, 8), 0, stream>>>(Wqkv, wqkvT, 1024, 3072);
  k_transpose_bf16<<<dim3(1024 / 32, 1024 / 32), dim3(32, 8), 0, stream>>>(Wout, woutT, 1024, 1024);
  k_rope<<<32 * 2048 / 256, 256, 0, stream>>>(cosTt, sinTt);
  k_gemm_qkv<<<dim3(24, 64), 256, 0, stream>>>(xb, wqkvT, bqkv, cosTt, sinTt, qb, kb, vpb);
  k_attn<<<dim3(16, 64), 256, 0, stream>>>(qb, kb, vpb, ao);
  k_gemm_out<<<dim3(1024 / 128, 8192 / 128), 256, 0, stream>>>(ao, woutT, bout, out,
                                                               8192, 1024, 1024);
}

// Round 17
// 193.717 us; speedup vs baseline: 1.0565x; 1.0565x over previous
//
#include <hip/hip_runtime.h>
#include <hip/hip_bf16.h>
#include <stdint.h>

#define DEVI __device__ __forceinline__

typedef __attribute__((ext_vector_type(8))) short bf16x8;
typedef __attribute__((ext_vector_type(4))) float f32x4;

DEVI float bf2f(short u) {
  union { unsigned int i; float f; } v;
  v.i = ((unsigned int)(unsigned short)u) << 16;
  return v.f;
}
DEVI short f2bf(float f) {
  union { float f; unsigned int i; } v; v.f = f;
  unsigned int r = v.i + 0x7FFFu + ((v.i >> 16) & 1u);  // RNE
  return (short)(r >> 16);
}

// LDS tile: row stride 64 shorts (128B), 16B-chunk XOR swizzle by (row&7).
DEVI bf16x8 ldsfrag(const short* t, int row, int k0) {
  int slot = k0 >> 3;
  return *(const bf16x8*)(t + row * 64 + ((slot ^ (row & 7)) << 3));
}

// async global->LDS, 16B per lane; LDS dest = uniform base + lane*16 (m97).
DEVI void gload16(const void* g, void* l) {
  __builtin_amdgcn_global_load_lds((const __attribute__((address_space(1))) void*)g,
                                   (__attribute__((address_space(3))) void*)l, 16, 0, 0);
}

// ---------------- fused prep: x cvt (bf16) + Wqkv^T + Wout^T + RoPE tables ----------
// 1D grid, 256 thr. Block ranges:
//   [0, 8192)          : cvt x (4 f32 -> bf16 per thread)
//   [8192, 11264)      : transpose Wqkv (1024x3072 -> 3072x1024), 96x32 tiles
//   [11264, 12288)     : transpose Wout (1024x1024 -> 1024x1024), 32x32 tiles
//   [12288, 12544)     : RoPE tables cos/sin[i][s] (transposed)
__global__ __launch_bounds__(256) void k_prep(const float* __restrict__ x,
                                              const float* __restrict__ Wqkv,
                                              const float* __restrict__ Wout,
                                              short* __restrict__ xb,
                                              short* __restrict__ wqkvT,
                                              short* __restrict__ woutT,
                                              float* __restrict__ cosTt,
                                              float* __restrict__ sinTt) {
  const int blk = blockIdx.x, tid = threadIdx.x;
  if (blk < 8192) {
    const int i = blk * 256 + tid;
    float4 v = ((const float4*)x)[i];
    short4 o;
    o.x = f2bf(v.x); o.y = f2bf(v.y); o.z = f2bf(v.z); o.w = f2bf(v.w);
    ((short4*)xb)[i] = o;
  } else if (blk < 12288) {
    // transpose+convert a 32x32 tile of W (R x C f32 -> C x R bf16)
    __shared__ float tile[32][33];
    const float* in;
    short* outp;
    int R, C, tb;
    if (blk < 11264) { in = Wqkv; outp = wqkvT; R = 1024; C = 3072; tb = blk - 8192; }
    else             { in = Wout; outp = woutT; R = 1024; C = 1024; tb = blk - 11264; }
    const int tilesC = C >> 5;
    const int c0 = (tb % tilesC) * 32, r0 = (tb / tilesC) * 32;
    const int tx = tid & 31, ty = tid >> 5;
    for (int i = ty; i < 32; i += 8) tile[i][tx] = in[(size_t)(r0 + i) * C + c0 + tx];
    __syncthreads();
    for (int i = ty; i < 32; i += 8) outp[(size_t)(c0 + i) * R + r0 + tx] = f2bf(tile[tx][i]);
  } else {
    const int idx = (blk - 12288) * 256 + tid;  // 32*2048
    const int i = idx >> 11, s = idx & 2047;
    float inv = exp2f(-0.41524101186092034f * (float)i);
    float f = (float)s * inv;
    cosTt[idx] = cosf(f);
    sinTt[idx] = sinf(f);
  }
}

// ---------------- fused QKV GEMM + bias + RoPE + head-split/permute (R10-proven) -------
__global__ __launch_bounds__(256) void k_gemm_qkv(const short* __restrict__ A,
                                                  const short* __restrict__ BT,
                                                  const float* __restrict__ bias,
                                                  const float* __restrict__ cosTt,
                                                  const float* __restrict__ sinTt,
                                                  short* __restrict__ qo,
                                                  short* __restrict__ ko,
                                                  short* __restrict__ vp) {
  __shared__ __align__(16) short smem[17408];  // K-loop: As|Bs; epi: [128][136]
  short* As = smem;
  short* Bs = smem + 8192;
  const int tid = threadIdx.x;
  const int lane = tid & 63, wid = tid >> 6;
  const int ln = lane & 15, grp = lane >> 4;
  const int wm = wid >> 1, wn = wid & 1;
  const int bx = blockIdx.x;
  const int r0 = blockIdx.y * 128, c0 = bx * 128;
  const int K = 1024;

  const short* aSrc[4];
  const short* bSrc[4];
  int ldst[4];
#pragma unroll
  for (int j = 0; j < 4; ++j) {
    int chunk = wid * 256 + j * 64 + lane;
    int row = chunk >> 3, gs = (chunk & 7) ^ (row & 7);
    aSrc[j] = A + (size_t)(r0 + row) * K + gs * 8;
    bSrc[j] = BT + (size_t)(c0 + row) * K + gs * 8;
    ldst[j] = (wid * 256 + j * 64) * 8;
  }

  f32x4 acc[4][4];
#pragma unroll
  for (int i = 0; i < 4; ++i)
#pragma unroll
    for (int j = 0; j < 4; ++j) acc[i][j] = (f32x4){0.f, 0.f, 0.f, 0.f};

  for (int kt = 0; kt < 16; ++kt) {
    __syncthreads();
#pragma unroll
    for (int j = 0; j < 4; ++j) {
      gload16(aSrc[j], &As[ldst[j]]);
      gload16(bSrc[j], &Bs[ldst[j]]);
      aSrc[j] += 64;
      bSrc[j] += 64;
    }
    __syncthreads();
#pragma unroll
    for (int ks = 0; ks < 2; ++ks) {
      const int k0 = ks * 32 + grp * 8;
      bf16x8 af[4], bfr[4];
#pragma unroll
      for (int mi = 0; mi < 4; ++mi) af[mi] = ldsfrag(As, wm * 64 + mi * 16 + ln, k0);
#pragma unroll
      for (int ni = 0; ni < 4; ++ni) bfr[ni] = ldsfrag(Bs, wn * 64 + ni * 16 + ln, k0);
#pragma unroll
      for (int mi = 0; mi < 4; ++mi)
#pragma unroll
        for (int ni = 0; ni < 4; ++ni)
          acc[mi][ni] = __builtin_amdgcn_mfma_f32_16x16x32_bf16(af[mi], bfr[ni], acc[mi][ni], 0, 0, 0);
    }
  }

  // ---------------- fused epilogue ----------------
  __syncthreads();
  const int third = bx >> 3;          // 0=q, 1=k, 2=v
  const int h0 = (bx & 7) * 2;
  const int b = r0 >> 11, sb = r0 & 2047;

  if (third < 2) {
    const float QS = (third == 0) ? 0.18033688011112042f : 1.0f;  // q: 0.125*log2(e)
#pragma unroll
    for (int mi = 0; mi < 4; ++mi) {
      const int s0 = sb + wm * 64 + mi * 16 + grp * 4;
      const int rowb = (wm * 64 + mi * 16 + grp * 4) * 136 + wn * 64;
#pragma unroll
      for (int ni = 0; ni < 2; ++ni) {
        const int d1 = ni * 16 + ln;
        float4 cv = *(const float4*)(cosTt + d1 * 2048 + s0);
        float4 sv = *(const float4*)(sinTt + d1 * 2048 + s0);
        const float b1 = bias[c0 + wn * 64 + d1];
        const float b2 = bias[c0 + wn * 64 + d1 + 32];
#pragma unroll
        for (int r = 0; r < 4; ++r) {
          float x1 = acc[mi][ni][r] + b1;
          float x2 = acc[mi][ni + 2][r] + b2;
          float c = ((const float*)&cv)[r], s = ((const float*)&sv)[r];
          smem[rowb + r * 136 + d1]      = f2bf((x1 * c - x2 * s) * QS);
          smem[rowb + r * 136 + d1 + 32] = f2bf((x1 * s + x2 * c) * QS);
        }
      }
    }
    __syncthreads();
    const int rloc = tid >> 1, ph = tid & 1;
    const int bh = b * 16 + h0 + ph;
    short* dst = (third == 0 ? qo : ko) + ((size_t)bh * 2048 + sb + rloc) * 64;
    const short* src = smem + rloc * 136 + ph * 64;
#pragma unroll
    for (int j = 0; j < 8; ++j) *(int4*)(dst + j * 8) = *(const int4*)(src + j * 8);
  } else {
#pragma unroll
    for (int mi = 0; mi < 4; ++mi) {
      const int rowb = (wm * 64 + mi * 16 + grp * 4) * 136 + wn * 64;
#pragma unroll
      for (int ni = 0; ni < 4; ++ni) {
        const float bv = bias[c0 + wn * 64 + ni * 16 + ln];
#pragma unroll
        for (int r = 0; r < 4; ++r)
          smem[rowb + r * 136 + ni * 16 + ln] = f2bf(acc[mi][ni][r] + bv);
      }
    }
    __syncthreads();
#pragma unroll
    for (int i = 0; i < 8; ++i) {
      const int g = i * 256 + tid;
      const int ph = g >> 10, tt = (g >> 9) & 1, cc2 = g & 511;
      const int ks = cc2 >> 8, mi = (cc2 >> 6) & 3, grp_ = (cc2 >> 4) & 3, ln_ = cc2 & 15;
      const int d = mi * 16 + ln_;
      bf16x8 o;
#pragma unroll
      for (int e = 0; e < 8; ++e) {
        const int key = tt * 64 + 32 * ks + 16 * (e >> 2) + 4 * grp_ + (e & 3);
        o[e] = smem[key * 136 + ph * 64 + d];
      }
      const int bh = b * 16 + h0 + ph;
      const int tg = (sb >> 6) + tt;
      *(bf16x8*)(vp + ((size_t)bh * 32 + tg) * 4096 + cc2 * 8) = o;
    }
  }
}

// ---------------- plain bf16 MFMA GEMM (out-proj, R10-proven): f32 out ----------------
__global__ __launch_bounds__(256) void k_gemm_out(const short* __restrict__ A,
                                                  const short* __restrict__ BT,
                                                  const float* __restrict__ bias,
                                                  float* __restrict__ outp,
                                                  int M, int N, int K) {
  __shared__ __align__(16) short As[128 * 64];
  __shared__ __align__(16) short Bs[128 * 64];
  const int tid = threadIdx.x;
  const int lane = tid & 63, wid = tid >> 6;
  const int ln = lane & 15, grp = lane >> 4;
  const int wm = wid >> 1, wn = wid & 1;
  const int r0 = blockIdx.y * 128, c0 = blockIdx.x * 128;

  const short* aSrc[4];
  const short* bSrc[4];
  int ldst[4];
#pragma unroll
  for (int j = 0; j < 4; ++j) {
    int chunk = wid * 256 + j * 64 + lane;
    int row = chunk >> 3, gs = (chunk & 7) ^ (row & 7);
    aSrc[j] = A + (size_t)(r0 + row) * K + gs * 8;
    bSrc[j] = BT + (size_t)(c0 + row) * K + gs * 8;
    ldst[j] = (wid * 256 + j * 64) * 8;
  }

  f32x4 acc[4][4];
#pragma unroll
  for (int i = 0; i < 4; ++i)
#pragma unroll
    for (int j = 0; j < 4; ++j) acc[i][j] = (f32x4){0.f, 0.f, 0.f, 0.f};

  const int nkt = K >> 6;
  for (int kt = 0; kt < nkt; ++kt) {
    __syncthreads();
#pragma unroll
    for (int j = 0; j < 4; ++j) {
      gload16(aSrc[j], &As[ldst[j]]);
      gload16(bSrc[j], &Bs[ldst[j]]);
      aSrc[j] += 64;
      bSrc[j] += 64;
    }
    __syncthreads();
#pragma unroll
    for (int ks = 0; ks < 2; ++ks) {
      const int k0 = ks * 32 + grp * 8;
      bf16x8 af[4], bfr[4];
#pragma unroll
      for (int mi = 0; mi < 4; ++mi) af[mi] = ldsfrag(As, wm * 64 + mi * 16 + ln, k0);
#pragma unroll
      for (int ni = 0; ni < 4; ++ni) bfr[ni] = ldsfrag(Bs, wn * 64 + ni * 16 + ln, k0);
#pragma unroll
      for (int mi = 0; mi < 4; ++mi)
#pragma unroll
        for (int ni = 0; ni < 4; ++ni)
          acc[mi][ni] = __builtin_amdgcn_mfma_f32_16x16x32_bf16(af[mi], bfr[ni], acc[mi][ni], 0, 0, 0);
    }
  }
#pragma unroll
  for (int ni = 0; ni < 4; ++ni) {
    const int col = c0 + wn * 64 + ni * 16 + ln;
    const float bv = bias[col];
#pragma unroll
    for (int mi = 0; mi < 4; ++mi) {
#pragma unroll
      for (int r = 0; r < 4; ++r) {
        const int rowg = r0 + wm * 64 + mi * 16 + grp * 4 + r;
        outp[(size_t)rowg * N + col] = acc[mi][ni][r] + bv;
      }
    }
  }
}

// ---------------- flash attention (R15-proven): KVBLK=128, runtime-cur dbuf + T1 ------
__global__ __launch_bounds__(256) void k_attn(const short* __restrict__ Q,
                                              const short* __restrict__ Kk,
                                              const short* __restrict__ Vp,
                                              short* __restrict__ out) {
  __shared__ __align__(16) short smem[2 * 16384];  // buf: K[128][64] 8192sh | V 8192sh
  const int tid = threadIdx.x;
  const int lane = tid & 63, wid = tid >> 6;
  const int ln = lane & 15, grp = lane >> 4;
  const int L = blockIdx.y * 16 + blockIdx.x;       // 0..1023
  const int W = (L & 7) * 128 + (L >> 3);           // XCD-chunked work id
  const int qt = W & 15, bh = W >> 4;
  const int b = bh >> 4, h = bh & 15;

  bf16x8 qf[2][2];
#pragma unroll
  for (int g = 0; g < 2; ++g)
#pragma unroll
    for (int ks = 0; ks < 2; ++ks)
      qf[g][ks] = *(const bf16x8*)(Q + ((size_t)bh * 2048 + qt * 128 + wid * 32 + g * 16 + ln) * 64
                                   + ks * 32 + grp * 8);

  // staging: 1024 K-chunks + 1024 V-chunks of 16B per tile; 4 each per thread
  const short* kSrc[4];
  const short* vSrc[4];
  int ldk[4], ldv[4];
  {
    const short* kt0 = Kk + (size_t)bh * 2048 * 64;
    const short* vt0 = Vp + (size_t)bh * 32 * 4096;
#pragma unroll
    for (int j = 0; j < 4; ++j) {
      int c = j * 256 + wid * 64 + lane;
      int row = c >> 3, gs = (c & 7) ^ (row & 7);
      kSrc[j] = kt0 + (size_t)row * 64 + gs * 8;
      ldk[j] = (j * 256 + wid * 64) * 8;
      vSrc[j] = vt0 + (size_t)c * 8;
      ldv[j] = 8192 + (j * 256 + wid * 64) * 8;
    }
  }

  f32x4 acc[2][4];
  f32x4 accl[2];
#pragma unroll
  for (int g = 0; g < 2; ++g) {
    accl[g] = (f32x4){0.f, 0.f, 0.f, 0.f};
#pragma unroll
    for (int i = 0; i < 4; ++i) acc[g][i] = (f32x4){0.f, 0.f, 0.f, 0.f};
  }
  bf16x8 ones;
#pragma unroll
  for (int e = 0; e < 8; ++e) ones[e] = (short)0x3F80;  // bf16 1.0

  union PU { bf16x8 v; unsigned int u[4]; };

  // prologue: stage tile 0 into buf 0
#pragma unroll
  for (int j = 0; j < 4; ++j) {
    gload16(kSrc[j], &smem[ldk[j]]);
    gload16(vSrc[j], &smem[ldv[j]]);
    kSrc[j] += 8192;
    vSrc[j] += 8192;
  }
  __syncthreads();

  int cur = 0;
  for (int t = 0; t < 16; ++t) {
    if (t < 15) {
      const int bo = (cur ^ 1) * 16384;
#pragma unroll
      for (int j = 0; j < 4; ++j) {
        gload16(kSrc[j], &smem[bo + ldk[j]]);
        gload16(vSrc[j], &smem[bo + ldv[j]]);
        kSrc[j] += 8192;
        vSrc[j] += 8192;
      }
    }
    const short* Kb = smem + cur * 16384;
    const short* Vb = Kb + 8192;

    // ---- S^T = K Q^T : sf[g][ni][r] = S'[key=ni*16+grp*4+r][q(g)], ni 0..7 ----
    f32x4 sf[2][8];
#pragma unroll
    for (int g = 0; g < 2; ++g)
#pragma unroll
      for (int ni = 0; ni < 8; ++ni) sf[g][ni] = (f32x4){0.f, 0.f, 0.f, 0.f};
#pragma unroll
    for (int ks = 0; ks < 2; ++ks) {
      bf16x8 kf[8];
#pragma unroll
      for (int ni = 0; ni < 8; ++ni) kf[ni] = ldsfrag(Kb, ni * 16 + ln, ks * 32 + grp * 8);
      __builtin_amdgcn_s_setprio(1);
#pragma unroll
      for (int g = 0; g < 2; ++g)
#pragma unroll
        for (int ni = 0; ni < 8; ++ni)
          sf[g][ni] = __builtin_amdgcn_mfma_f32_16x16x32_bf16(kf[ni], qf[g][ks], sf[g][ni], 0, 0, 0);
      __builtin_amdgcn_s_setprio(0);
    }

    // ---- p = exp2(s); pack to bf16 (asm v_cvt_pk, R7-proven) ----
    PU pbf[2][4];
#pragma unroll
    for (int g = 0; g < 2; ++g) {
#pragma unroll
      for (int ni = 0; ni < 8; ++ni) {
        f32x4 s = sf[g][ni];
#pragma unroll
        for (int r = 0; r < 4; ++r) s[r] = __builtin_amdgcn_exp2f(s[r]);
        sf[g][ni] = s;
      }
#pragma unroll
      for (int ks2 = 0; ks2 < 4; ++ks2)
#pragma unroll
        for (int j = 0; j < 4; ++j) {
          float lo = sf[g][2 * ks2 + (j >> 1)][(j & 1) * 2];
          float hi = sf[g][2 * ks2 + (j >> 1)][(j & 1) * 2 + 1];
          unsigned int rr;
          asm("v_cvt_pk_bf16_f32 %0, %1, %2" : "=v"(rr) : "v"(lo), "v"(hi));
          pbf[g][ks2].u[j] = rr;
        }
    }

    // ---- O^T += V^T P ; l += 1^T P  (ks2 over 4 key-slices of 32) ----
#pragma unroll
    for (int ks2 = 0; ks2 < 4; ++ks2) {
      bf16x8 vf[4];
#pragma unroll
      for (int mi = 0; mi < 4; ++mi)
        vf[mi] = *(const bf16x8*)(Vb + (ks2 * 256 + mi * 64 + lane) * 8);
      __builtin_amdgcn_s_setprio(1);
#pragma unroll
      for (int g = 0; g < 2; ++g) {
#pragma unroll
        for (int mi = 0; mi < 4; ++mi)
          acc[g][mi] = __builtin_amdgcn_mfma_f32_16x16x32_bf16(vf[mi], pbf[g][ks2].v, acc[g][mi], 0, 0, 0);
        accl[g] = __builtin_amdgcn_mfma_f32_16x16x32_bf16(ones, pbf[g][ks2].v, accl[g], 0, 0, 0);
      }
      __builtin_amdgcn_s_setprio(0);
    }

    __syncthreads();
    cur ^= 1;
  }

  // ---- epilogue: O^T/l -> swizzled LDS [q][d] -> coalesced global ----
#pragma unroll
  for (int g = 0; g < 2; ++g) {
    const float inv = 1.0f / accl[g][0];
    const int q = wid * 32 + g * 16 + ln;
#pragma unroll
    for (int mi = 0; mi < 4; ++mi) {
      short4 p;
      p.x = f2bf(acc[g][mi][0] * inv);
      p.y = f2bf(acc[g][mi][1] * inv);
      p.z = f2bf(acc[g][mi][2] * inv);
      p.w = f2bf(acc[g][mi][3] * inv);
      int slot = mi * 2 + (grp >> 1);
      *(short4*)(&smem[q * 64 + ((slot ^ (q & 7)) << 3) + (grp & 1) * 4]) = p;
    }
  }
  __syncthreads();
  {
    const int row = tid >> 1, half = tid & 1;
#pragma unroll
    for (int j = 0; j < 4; ++j) {
      int c = half * 4 + j;
      int4 v = *(const int4*)(&smem[row * 64 + ((c ^ (row & 7)) << 3)]);
      *(int4*)(out + ((size_t)b * 2048 + qt * 128 + row) * 1024 + h * 64 + c * 8) = v;
    }
  }
}

extern "C" void kernel_launch(void* const* d_in, const int* in_sizes, int n_in,
                              void* d_out, int out_size, void* d_ws, size_t ws_size,
                              hipStream_t stream) {
  const float* x    = (const float*)d_in[0];
  const float* Wqkv = (const float*)d_in[1];
  const float* bqkv = (const float*)d_in[2];
  const float* Wout = (const float*)d_in[3];
  const float* bout = (const float*)d_in[4];
  float* out = (float*)d_out;

  char* p = (char*)d_ws;
  short* xb    = (short*)p; p += (size_t)8192 * 1024 * 2;
  short* wqkvT = (short*)p; p += (size_t)3072 * 1024 * 2;
  short* woutT = (short*)p; p += (size_t)1024 * 1024 * 2;
  float* cosTt = (float*)p; p += (size_t)32 * 2048 * 4;
  float* sinTt = (float*)p; p += (size_t)32 * 2048 * 4;
  short* qb    = (short*)p; p += (size_t)64 * 2048 * 64 * 2;
  short* kb    = (short*)p; p += (size_t)64 * 2048 * 64 * 2;
  short* vpb   = (short*)p; p += (size_t)64 * 2048 * 64 * 2;
  short* ao    = (short*)p; p += (size_t)8192 * 1024 * 2;

  k_prep<<<12544, 256, 0, stream>>>(x, Wqkv, Wout, xb, wqkvT, woutT, cosTt, sinTt);
  k_gemm_qkv<<<dim3(24, 64), 256, 0, stream>>>(xb, wqkvT, bqkv, cosTt, sinTt, qb, kb, vpb);
  k_attn<<<dim3(16, 64), 256, 0, stream>>>(qb, kb, vpb, ao);
  k_gemm_out<<<dim3(1024 / 128, 8192 / 128), 256, 0, stream>>>(ao, woutT, bout, out,
                                                               8192, 1024, 1024);
}